// Round 13
// baseline (75.575 us; speedup 1.0000x reference)
//
#include <hip/hip_runtime.h>
#include <hip/hip_bf16.h>
#include <math.h>

#define NRES   4096
#define NBATCH 1024
#define NIN    128
#define NOUT   64
// K layout: [0,4096) x/W_res bf16 | [4096,4224) hiP*hiW | [4224,4352) hiP*loW
//           [4352,4480) loP*hiW | [4480,4544) hiT*hiWo | [4544,4608) hiT*loWo | [4608,4672) loT*hiWo
#define KT     4672
#define KQ     (KT / 4)
#define TILES  73
#define MN     ((size_t)NBATCH * NRES)

typedef __bf16 bf16x8 __attribute__((ext_vector_type(8)));
typedef __bf16 bf16x4 __attribute__((ext_vector_type(4)));
typedef float  f32x4  __attribute__((ext_vector_type(4)));

__device__ __forceinline__ float lo_part(float f) {
    return f - (float)(__bf16)f;
}

__device__ __forceinline__ void gload_lds16(const __bf16* g, __bf16* l) {
    __builtin_amdgcn_global_load_lds(
        (const __attribute__((address_space(1))) unsigned int*)g,
        (__attribute__((address_space(3))) unsigned int*)l, 16, 0, 0);
}

// Merged pack: unit id < BU packs Bbuf (W_res/W_in/W_out), else packs Abuf.
#define BU ((unsigned)NRES * KQ)     // 4,784,128 bf16x4 units
#define AU ((unsigned)NBATCH * KQ)   // 1,196,032

__global__ __launch_bounds__(256) void pack_all(
    const float* __restrict__ x, const float* __restrict__ passed,
    const float* __restrict__ lastOut, const float* __restrict__ lastPred,
    const float* __restrict__ prob, const float* __restrict__ rand_num,
    const float* __restrict__ W_res, const float* __restrict__ W_in,
    const float* __restrict__ W_out,
    __bf16* __restrict__ Abuf, __bf16* __restrict__ Bbuf)
{
    unsigned id = blockIdx.x * 256u + threadIdx.x;
    f32x4 v;
    __bf16* dst;
    if (id < BU) {
        unsigned n = id / KQ;
        unsigned k = (id - n * KQ) * 4u;
        if (k < 4096u) {
            v = *(const f32x4*)(W_res + (size_t)n * NRES + k);
        } else if (k < 4224u) {
            v = *(const f32x4*)(W_in + n * NIN + (k - 4096u));              // hi
        } else if (k < 4352u) {
            f32x4 f = *(const f32x4*)(W_in + n * NIN + (k - 4224u));        // lo (pairs hiP)
#pragma unroll
            for (int e = 0; e < 4; ++e) v[e] = lo_part(f[e]);
        } else if (k < 4480u) {
            v = *(const f32x4*)(W_in + n * NIN + (k - 4352u));              // hi (pairs loP)
        } else if (k < 4544u) {
            v = *(const f32x4*)(W_out + n * NOUT + (k - 4480u));            // hi
        } else if (k < 4608u) {
            f32x4 f = *(const f32x4*)(W_out + n * NOUT + (k - 4544u));      // lo
#pragma unroll
            for (int e = 0; e < 4; ++e) v[e] = lo_part(f[e]);
        } else {
            v = *(const f32x4*)(W_out + n * NOUT + (k - 4608u));            // hi
        }
        dst = Bbuf + (size_t)id * 4u;
    } else {
        unsigned aid = id - BU;
        if (aid >= AU) return;
        unsigned b = aid / KQ;
        unsigned k = (aid - b * KQ) * 4u;
        if (k < 4096u) {
            v = *(const f32x4*)(x + (size_t)b * NRES + k);
        } else if (k < 4224u) {
            v = *(const f32x4*)(passed + b * NIN + (k - 4096u));            // hi
        } else if (k < 4352u) {
            v = *(const f32x4*)(passed + b * NIN + (k - 4224u));            // hi (pairs loW)
        } else if (k < 4480u) {
            f32x4 f = *(const f32x4*)(passed + b * NIN + (k - 4352u));      // lo
#pragma unroll
            for (int e = 0; e < 4; ++e) v[e] = lo_part(f[e]);
        } else {
            const float* src = (rand_num[0] < prob[0]) ? lastOut : lastPred;
#pragma unroll
            for (int e = 0; e < 4; ++e) {
                unsigned kk = k + e;
                unsigned j; bool want_lo;
                if (kk < 4544u)      { j = kk - 4480u; want_lo = false; }
                else if (kk < 4608u) { j = kk - 4544u; want_lo = false; }
                else                 { j = kk - 4608u; want_lo = true;  }
                float f = src[j * NBATCH + b];
                v[e] = want_lo ? lo_part(f) : f;
            }
        }
        dst = Abuf + (size_t)aid * 4u;
    }
    bf16x4 o;
#pragma unroll
    for (int e = 0; e < 4; ++e) o[e] = (__bf16)v[e];
    *(bf16x4*)dst = o;
}

// 256x256 tile, 8 waves (2Mx4N), wave-tile 128x64, BK=64, split-K over z.
// R13 sync-minimal schedule: ONE vmcnt(0) + ONE barrier per K-tile, at ph0.
// All of tile t's chunks are staged during tile t-1 (2-4 phase lead), so the
// ph0 drain has no younger loads to wait on. The barrier then (a) makes the
// drain collective, (b) certifies all reads of buffer nxt finished (every
// wave's ph3(t-1) MFMA forced its ds_read completion). Phases 1-3 run with
// no syncs at all: waves drift, MFMA of one hides ds_read/stage of another.
// Staging spread c0,c2@ph0 / c3@ph1 / c1@ph2 smooths memory-pipe issue.
// bf16 partials; XCD-aware bijective block swizzle. NOTE: (512,1) mandatory —
// (512,4) spills the 128-reg accumulator (R11: 867MB scratch, 7x regression).
__global__ __launch_bounds__(512, 1) void gemm_kernel(
    const __bf16* __restrict__ Abuf, const __bf16* __restrict__ Bbuf,
    __bf16* __restrict__ part, int split)
{
    __shared__ __align__(16) __bf16 SH[2][32768];   // [buf][A 16384 | B 16384] elems

    const int t  = threadIdx.x;
    const int l  = t & 63;
    const int w  = t >> 6;     // 0..7
    const int wm = w >> 2;     // 0..1 : 128-row slab
    const int wn = w & 3;      // 0..3 : 64-col slab

    // XCD swizzle: dispatch id n -> XCD n%8; logical id o = (n%8)*(nwg/8) + n/8.
    const int nwg  = gridDim.x * gridDim.y * gridDim.z;
    const int cpx  = nwg >> 3;
    const int flat = blockIdx.x + gridDim.x * (blockIdx.y + gridDim.y * blockIdx.z);
    const int o    = (flat & 7) * cpx + (flat >> 3);
    const int bn   = o % gridDim.x;
    const int bm   = (o / gridDim.x) % gridDim.y;
    const int bz   = o / (gridDim.x * gridDim.y);

    const int qs = TILES / split, rs = TILES % split;
    const int t0 = bz * qs + (bz < rs ? bz : rs);
    const int nt = qs + (bz < rs ? 1 : 0);

    f32x4 acc[8][4] = {};

    // ---- staging precompute: 4 chunks x (2 x 16B per thread).
    // c0: A rows {0-63,128-191} (LDA(0)); c1: A rows {64-127,192-255} (LDA(1));
    // c2: B cols {0-31,+64k} (LDB(0));    c3: B cols {32-63,+64k} (LDB(1)).
    // LDS dest linear (gload_lds requirement); XOR swizzle on SOURCE column (rule #21).
    unsigned goff[4][2];
    int lE[4][2];
#pragma unroll
    for (int c = 0; c < 4; ++c) {
#pragma unroll
        for (int j = 0; j < 2; ++j) {
            int ui = j * 512 + t;              // unit 0..1023 within chunk
            int lr = ui >> 3;                  // 0..127
            int cb = (ui & 7) << 4;            // byte-in-row 0..112
            int rc;
            if (c == 0)      rc = (lr & 63) + ((lr >> 6) << 7);
            else if (c == 1) rc = 64 + (lr & 63) + ((lr >> 6) << 7);
            else if (c == 2) rc = (lr & 31) + ((lr >> 5) << 6);
            else             rc = 32 + (lr & 31) + ((lr >> 5) << 6);
            int cs = cb ^ ((rc & 7) << 4);     // swizzled source byte
            if (c < 2) {
                goff[c][j] = (unsigned)((bm * 256 + rc) * KT) + (cs >> 1);
                lE[c][j]   = rc * 64 + (cb >> 1);
            } else {
                goff[c][j] = (unsigned)((bn * 256 + rc) * KT) + (cs >> 1);
                lE[c][j]   = 16384 + rc * 64 + (cb >> 1);
            }
        }
    }

#define STAGEC(c, nxt, k0n)                                              \
    do {                                                                 \
        gload_lds16(((c) < 2 ? Abuf : Bbuf) + goff[c][0] + (k0n),        \
                    &SH[nxt][lE[c][0]]);                                 \
        gload_lds16(((c) < 2 ? Abuf : Bbuf) + goff[c][1] + (k0n),        \
                    &SH[nxt][lE[c][1]]);                                 \
    } while (0)

    // ---- fragment read ELEMENT offsets (swizzled); kk=1 is ^32 elems
    int eA[8], eB[4];
#pragma unroll
    for (int m = 0; m < 8; ++m) {
        int row = wm * 128 + m * 16 + (l & 15);
        eA[m] = row * 64 + (((((l >> 4) << 4)) ^ ((row & 7) << 4)) >> 1);
    }
#pragma unroll
    for (int n = 0; n < 4; ++n) {
        int col = wn * 64 + n * 16 + (l & 15);
        eB[n] = 16384 + col * 64 + (((((l >> 4) << 4)) ^ ((col & 7) << 4)) >> 1);
    }

    bf16x8 af[4][2], bfr[4][2];

#define BAR() do { asm volatile("" ::: "memory");                        \
                   __builtin_amdgcn_s_barrier();                         \
                   asm volatile("" ::: "memory"); } while (0)
#define VM(n) asm volatile("s_waitcnt vmcnt(" #n ")" ::: "memory")

#define LDA(qd, buf)                                                     \
    do {                                                                 \
        _Pragma("unroll")                                                \
        for (int m2 = 0; m2 < 4; ++m2) {                                 \
            af[m2][0] = *(const bf16x8*)&SH[buf][eA[(qd)*4 + m2]];       \
            af[m2][1] = *(const bf16x8*)&SH[buf][eA[(qd)*4 + m2] ^ 32];  \
        }                                                                \
    } while (0)

#define LDB(h, buf)                                                      \
    do {                                                                 \
        _Pragma("unroll")                                                \
        for (int n3 = 0; n3 < 2; ++n3) {                                 \
            bfr[(h)*2+n3][0] = *(const bf16x8*)&SH[buf][eB[(h)*2 + n3]]; \
            bfr[(h)*2+n3][1] = *(const bf16x8*)&SH[buf][eB[(h)*2+n3] ^ 32]; \
        }                                                                \
    } while (0)

#define MFMA16(qm, qn)                                                   \
    do {                                                                 \
        __builtin_amdgcn_s_setprio(1);                                   \
        _Pragma("unroll")                                                \
        for (int kk2 = 0; kk2 < 2; ++kk2)                                \
            _Pragma("unroll")                                            \
            for (int m2 = 0; m2 < 4; ++m2)                               \
                _Pragma("unroll")                                        \
                for (int n2 = 0; n2 < 2; ++n2)                           \
                    acc[(qm)*4+m2][(qn)*2+n2] =                          \
                        __builtin_amdgcn_mfma_f32_16x16x32_bf16(         \
                            af[m2][kk2], bfr[(qn)*2+n2][kk2],            \
                            acc[(qm)*4+m2][(qn)*2+n2], 0, 0, 0);         \
        __builtin_amdgcn_s_setprio(0);                                   \
    } while (0)

    // Prologue: issue tile t0's 4 chunks into buf0 (drained at the loop's
    // first VM(0)+BAR).
    {
        const int k00 = t0 * 64;
        STAGEC(0, 0, k00); STAGEC(2, 0, k00); STAGEC(3, 0, k00); STAGEC(1, 0, k00);
    }

    for (int tt = 0; tt < nt; ++tt) {
        const int cur = tt & 1;
        const int nxt = cur ^ 1;
        const bool pf = (tt + 1 < nt);
        const int k0n = (t0 + tt + 1) * 64;
        // ph0: drain tile t's chunks (issued >=2 phases ago; nothing younger
        // outstanding), barrier collectivizes + closes all reads of buf nxt.
        VM(0);
        BAR();
        if (pf) { STAGEC(0, nxt, k0n); STAGEC(2, nxt, k0n); }
        LDA(0, cur); LDB(0, cur);
        MFMA16(0, 0);
        // ph1: no sync
        if (pf) STAGEC(3, nxt, k0n);
        LDB(1, cur);
        MFMA16(0, 1);
        // ph2: no sync
        if (pf) STAGEC(1, nxt, k0n);
        LDA(1, cur);
        MFMA16(1, 0);
        // ph3: no sync
        MFMA16(1, 1);
    }

    // Split-K partial store, bf16 (halves partial traffic; quant err ~2e-3).
    // C/D layout: col = lane&15, row = (lane>>4)*4 + reg  [m89/m91-verified]
    __bf16* pz = part + (size_t)bz * MN;
    const int r0 = bm * 256 + wm * 128 + ((l >> 4) << 2);
    const int c0 = bn * 256 + wn * 64 + (l & 15);
#pragma unroll
    for (int m = 0; m < 8; ++m) {
#pragma unroll
        for (int i = 0; i < 4; ++i) {
            __bf16* prow = pz + (size_t)(r0 + m * 16 + i) * NRES;
#pragma unroll
            for (int n = 0; n < 4; ++n)
                prow[c0 + n * 16] = (__bf16)acc[m][n][i];
        }
    }
#undef STAGEC
#undef BAR
#undef VM
#undef LDA
#undef LDB
#undef MFMA16
}

__global__ __launch_bounds__(256) void epilogue_kernel(
    const __bf16* __restrict__ part, int split, const float* __restrict__ xin,
    const float* __restrict__ Bin, float* __restrict__ out)
{
    size_t id = (size_t)blockIdx.x * 256u + threadIdx.x;   // 524,288 units of 8
    size_t e  = id * 8;
    int c = (int)(e & (NRES - 1));
    float s[8] = {};
    for (int z = 0; z < split; ++z) {
        bf16x8 p = *(const bf16x8*)(part + (size_t)z * MN + e);
#pragma unroll
        for (int j = 0; j < 8; ++j) s[j] += (float)p[j];
    }
    f32x4 xv0 = *(const f32x4*)(xin + e);
    f32x4 xv1 = *(const f32x4*)(xin + e + 4);
    f32x4 bv0 = *(const f32x4*)(Bin + c);
    f32x4 bv1 = *(const f32x4*)(Bin + c + 4);
    f32x4 o0, o1;
#pragma unroll
    for (int j = 0; j < 4; ++j) {
        o0[j] = 0.1f * xv0[j] + 0.9f * tanhf(s[j]     + bv0[j]);
        o1[j] = 0.1f * xv1[j] + 0.9f * tanhf(s[j + 4] + bv1[j]);
    }
    *(f32x4*)(out + e)     = o0;
    *(f32x4*)(out + e + 4) = o1;
}

extern "C" void kernel_launch(void* const* d_in, const int* in_sizes, int n_in,
                              void* d_out, int out_size, void* d_ws, size_t ws_size,
                              hipStream_t stream) {
    (void)in_sizes; (void)n_in; (void)out_size;
    const float* passed     = (const float*)d_in[0];
    const float* lastOutput = (const float*)d_in[1];
    const float* lastPred   = (const float*)d_in[2];
    const float* x          = (const float*)d_in[3];
    const float* prob       = (const float*)d_in[4];
    const float* rand_num   = (const float*)d_in[5];
    const float* W_in       = (const float*)d_in[6];
    const float* W_res      = (const float*)d_in[7];
    const float* W_out      = (const float*)d_in[8];
    const float* B_in       = (const float*)d_in[9];
    float* out = (float*)d_out;

    const size_t AB = (size_t)(NBATCH + NRES) * KT * 2;   // 47,841,280 B
    __bf16* Abuf = (__bf16*)d_ws;
    __bf16* Bbuf = (__bf16*)((char*)d_ws + (size_t)NBATCH * KT * 2);
    __bf16* part = (__bf16*)((char*)d_ws + AB);

    // ws-guarded split-K factor (deterministic: ws_size fixed per session)
    int split = 1;
    if (ws_size >= AB + 4 * MN * sizeof(__bf16))      split = 4;
    else if (ws_size >= AB + 2 * MN * sizeof(__bf16)) split = 2;

    pack_all<<<(BU + AU) / 256, 256, 0, stream>>>(
        x, passed, lastOutput, lastPred, prob, rand_num,
        W_res, W_in, W_out, Abuf, Bbuf);

    dim3 grid(NRES / 256, NBATCH / 256, split);
    gemm_kernel<<<grid, 512, 0, stream>>>(Abuf, Bbuf, part, split);

    epilogue_kernel<<<2048, 256, 0, stream>>>(part, split, x, B_in, out);
}

// Round 14
// 72.437 us; speedup vs baseline: 1.0433x; 1.0433x over previous
//
#include <hip/hip_runtime.h>
#include <hip/hip_bf16.h>
#include <math.h>

#define NRES   4096
#define NBATCH 1024
#define NIN    128
#define NOUT   64
// K layout: [0,4096) x/W_res bf16 | [4096,4224) hiP*hiW | [4224,4352) hiP*loW
//           [4352,4480) loP*hiW | [4480,4544) hiT*hiWo | [4544,4608) hiT*loWo | [4608,4672) loT*hiWo
#define KT     4672
#define KQ     (KT / 4)
#define TILES  73
#define MN     ((size_t)NBATCH * NRES)

typedef __bf16 bf16x8 __attribute__((ext_vector_type(8)));
typedef __bf16 bf16x4 __attribute__((ext_vector_type(4)));
typedef float  f32x4  __attribute__((ext_vector_type(4)));

__device__ __forceinline__ float lo_part(float f) {
    return f - (float)(__bf16)f;
}

__device__ __forceinline__ void gload_lds16(const __bf16* g, __bf16* l) {
    __builtin_amdgcn_global_load_lds(
        (const __attribute__((address_space(1))) unsigned int*)g,
        (__attribute__((address_space(3))) unsigned int*)l, 16, 0, 0);
}

// Merged pack: unit id < BU packs Bbuf (W_res/W_in/W_out), else packs Abuf.
#define BU ((unsigned)NRES * KQ)     // 4,784,128 bf16x4 units
#define AU ((unsigned)NBATCH * KQ)   // 1,196,032

__global__ __launch_bounds__(256) void pack_all(
    const float* __restrict__ x, const float* __restrict__ passed,
    const float* __restrict__ lastOut, const float* __restrict__ lastPred,
    const float* __restrict__ prob, const float* __restrict__ rand_num,
    const float* __restrict__ W_res, const float* __restrict__ W_in,
    const float* __restrict__ W_out,
    __bf16* __restrict__ Abuf, __bf16* __restrict__ Bbuf)
{
    unsigned id = blockIdx.x * 256u + threadIdx.x;
    f32x4 v;
    __bf16* dst;
    if (id < BU) {
        unsigned n = id / KQ;
        unsigned k = (id - n * KQ) * 4u;
        if (k < 4096u) {
            v = *(const f32x4*)(W_res + (size_t)n * NRES + k);
        } else if (k < 4224u) {
            v = *(const f32x4*)(W_in + n * NIN + (k - 4096u));              // hi
        } else if (k < 4352u) {
            f32x4 f = *(const f32x4*)(W_in + n * NIN + (k - 4224u));        // lo (pairs hiP)
#pragma unroll
            for (int e = 0; e < 4; ++e) v[e] = lo_part(f[e]);
        } else if (k < 4480u) {
            v = *(const f32x4*)(W_in + n * NIN + (k - 4352u));              // hi (pairs loP)
        } else if (k < 4544u) {
            v = *(const f32x4*)(W_out + n * NOUT + (k - 4480u));            // hi
        } else if (k < 4608u) {
            f32x4 f = *(const f32x4*)(W_out + n * NOUT + (k - 4544u));      // lo
#pragma unroll
            for (int e = 0; e < 4; ++e) v[e] = lo_part(f[e]);
        } else {
            v = *(const f32x4*)(W_out + n * NOUT + (k - 4608u));            // hi
        }
        dst = Bbuf + (size_t)id * 4u;
    } else {
        unsigned aid = id - BU;
        if (aid >= AU) return;
        unsigned b = aid / KQ;
        unsigned k = (aid - b * KQ) * 4u;
        if (k < 4096u) {
            v = *(const f32x4*)(x + (size_t)b * NRES + k);
        } else if (k < 4224u) {
            v = *(const f32x4*)(passed + b * NIN + (k - 4096u));            // hi
        } else if (k < 4352u) {
            v = *(const f32x4*)(passed + b * NIN + (k - 4224u));            // hi (pairs loW)
        } else if (k < 4480u) {
            f32x4 f = *(const f32x4*)(passed + b * NIN + (k - 4352u));      // lo
#pragma unroll
            for (int e = 0; e < 4; ++e) v[e] = lo_part(f[e]);
        } else {
            const float* src = (rand_num[0] < prob[0]) ? lastOut : lastPred;
#pragma unroll
            for (int e = 0; e < 4; ++e) {
                unsigned kk = k + e;
                unsigned j; bool want_lo;
                if (kk < 4544u)      { j = kk - 4480u; want_lo = false; }
                else if (kk < 4608u) { j = kk - 4544u; want_lo = false; }
                else                 { j = kk - 4608u; want_lo = true;  }
                float f = src[j * NBATCH + b];
                v[e] = want_lo ? lo_part(f) : f;
            }
        }
        dst = Abuf + (size_t)aid * 4u;
    }
    bf16x4 o;
#pragma unroll
    for (int e = 0; e < 4; ++e) o[e] = (__bf16)v[e];
    *(bf16x4*)dst = o;
}

// 256x256 tile, 8 waves (2Mx4N), wave-tile 128x64, BK=64, split-K over z.
// R12 schedule (best of 5 variants): 4-phase, one chunk staged per phase in
// consumption order (c0,c2,c3,c1), counted vmcnt(4), 3 barriers per K-tile.
// R14: split-K partial store in MFMA-NATIVE layout, bf16x4 vectorized —
// offset = blk*65536 + w*8192 + m*1024 + n*256 + l*4 (+i). 32 coalesced 8B
// stores/thread vs 128 scalar 2B. Epilogue inverts the mapping.
// NOTE: (512,1) mandatory — (512,4) spills the 128-reg accumulator (R11).
__global__ __launch_bounds__(512, 1) void gemm_kernel(
    const __bf16* __restrict__ Abuf, const __bf16* __restrict__ Bbuf,
    __bf16* __restrict__ part, int split)
{
    __shared__ __align__(16) __bf16 SH[2][32768];   // [buf][A 16384 | B 16384] elems

    const int t  = threadIdx.x;
    const int l  = t & 63;
    const int w  = t >> 6;     // 0..7
    const int wm = w >> 2;     // 0..1 : 128-row slab
    const int wn = w & 3;      // 0..3 : 64-col slab

    // XCD swizzle: dispatch id n -> XCD n%8; logical id o = (n%8)*(nwg/8) + n/8.
    const int nwg  = gridDim.x * gridDim.y * gridDim.z;
    const int cpx  = nwg >> 3;
    const int flat = blockIdx.x + gridDim.x * (blockIdx.y + gridDim.y * blockIdx.z);
    const int o    = (flat & 7) * cpx + (flat >> 3);
    const int bn   = o % gridDim.x;
    const int bm   = (o / gridDim.x) % gridDim.y;
    const int bz   = o / (gridDim.x * gridDim.y);

    const int qs = TILES / split, rs = TILES % split;
    const int t0 = bz * qs + (bz < rs ? bz : rs);
    const int nt = qs + (bz < rs ? 1 : 0);

    f32x4 acc[8][4] = {};

    // ---- staging precompute: 4 chunks x (2 x 16B per thread).
    // c0: A rows {0-63,128-191} (LDA(0)); c1: A rows {64-127,192-255} (LDA(1));
    // c2: B cols {0-31,+64k} (LDB(0));    c3: B cols {32-63,+64k} (LDB(1)).
    // LDS dest linear (gload_lds requirement); XOR swizzle on SOURCE column (rule #21).
    unsigned goff[4][2];
    int lE[4][2];
#pragma unroll
    for (int c = 0; c < 4; ++c) {
#pragma unroll
        for (int j = 0; j < 2; ++j) {
            int ui = j * 512 + t;              // unit 0..1023 within chunk
            int lr = ui >> 3;                  // 0..127
            int cb = (ui & 7) << 4;            // byte-in-row 0..112
            int rc;
            if (c == 0)      rc = (lr & 63) + ((lr >> 6) << 7);
            else if (c == 1) rc = 64 + (lr & 63) + ((lr >> 6) << 7);
            else if (c == 2) rc = (lr & 31) + ((lr >> 5) << 6);
            else             rc = 32 + (lr & 31) + ((lr >> 5) << 6);
            int cs = cb ^ ((rc & 7) << 4);     // swizzled source byte
            if (c < 2) {
                goff[c][j] = (unsigned)((bm * 256 + rc) * KT) + (cs >> 1);
                lE[c][j]   = rc * 64 + (cb >> 1);
            } else {
                goff[c][j] = (unsigned)((bn * 256 + rc) * KT) + (cs >> 1);
                lE[c][j]   = 16384 + rc * 64 + (cb >> 1);
            }
        }
    }

#define STAGEC(c, nxt, k0n)                                              \
    do {                                                                 \
        gload_lds16(((c) < 2 ? Abuf : Bbuf) + goff[c][0] + (k0n),        \
                    &SH[nxt][lE[c][0]]);                                 \
        gload_lds16(((c) < 2 ? Abuf : Bbuf) + goff[c][1] + (k0n),        \
                    &SH[nxt][lE[c][1]]);                                 \
    } while (0)

    // ---- fragment read ELEMENT offsets (swizzled); kk=1 is ^32 elems
    int eA[8], eB[4];
#pragma unroll
    for (int m = 0; m < 8; ++m) {
        int row = wm * 128 + m * 16 + (l & 15);
        eA[m] = row * 64 + (((((l >> 4) << 4)) ^ ((row & 7) << 4)) >> 1);
    }
#pragma unroll
    for (int n = 0; n < 4; ++n) {
        int col = wn * 64 + n * 16 + (l & 15);
        eB[n] = 16384 + col * 64 + (((((l >> 4) << 4)) ^ ((col & 7) << 4)) >> 1);
    }

    bf16x8 af[4][2], bfr[4][2];

#define BAR() do { asm volatile("" ::: "memory");                        \
                   __builtin_amdgcn_s_barrier();                         \
                   asm volatile("" ::: "memory"); } while (0)
#define VM(n) asm volatile("s_waitcnt vmcnt(" #n ")" ::: "memory")

#define LDA(qd, buf)                                                     \
    do {                                                                 \
        _Pragma("unroll")                                                \
        for (int m2 = 0; m2 < 4; ++m2) {                                 \
            af[m2][0] = *(const bf16x8*)&SH[buf][eA[(qd)*4 + m2]];       \
            af[m2][1] = *(const bf16x8*)&SH[buf][eA[(qd)*4 + m2] ^ 32];  \
        }                                                                \
    } while (0)

#define LDB(h, buf)                                                      \
    do {                                                                 \
        _Pragma("unroll")                                                \
        for (int n3 = 0; n3 < 2; ++n3) {                                 \
            bfr[(h)*2+n3][0] = *(const bf16x8*)&SH[buf][eB[(h)*2 + n3]]; \
            bfr[(h)*2+n3][1] = *(const bf16x8*)&SH[buf][eB[(h)*2+n3] ^ 32]; \
        }                                                                \
    } while (0)

#define MFMA16(qm, qn)                                                   \
    do {                                                                 \
        __builtin_amdgcn_s_setprio(1);                                   \
        _Pragma("unroll")                                                \
        for (int kk2 = 0; kk2 < 2; ++kk2)                                \
            _Pragma("unroll")                                            \
            for (int m2 = 0; m2 < 4; ++m2)                               \
                _Pragma("unroll")                                        \
                for (int n2 = 0; n2 < 2; ++n2)                           \
                    acc[(qm)*4+m2][(qn)*2+n2] =                          \
                        __builtin_amdgcn_mfma_f32_16x16x32_bf16(         \
                            af[m2][kk2], bfr[(qn)*2+n2][kk2],            \
                            acc[(qm)*4+m2][(qn)*2+n2], 0, 0, 0);         \
        __builtin_amdgcn_s_setprio(0);                                   \
    } while (0)

    // Prologue: stage tile t0 in consumption order; retire c0,c2 (c3,c1 in flight).
    {
        const int k00 = t0 * 64;
        STAGEC(0, 0, k00); STAGEC(2, 0, k00); STAGEC(3, 0, k00); STAGEC(1, 0, k00);
        VM(4);
        BAR();
    }

    for (int tt = 0; tt < nt - 1; ++tt) {
        const int cur = tt & 1;
        const int nxt = cur ^ 1;
        const int k0n = (t0 + tt + 1) * 64;
        // ph0: read c0,c2(t) [retired]; stage c0(t+1); retire c3(t)
        LDA(0, cur); LDB(0, cur);
        STAGEC(0, nxt, k0n);
        VM(4);
        BAR();
        MFMA16(0, 0);
        // ph1: read c3(t); stage c2(t+1); retire c1(t)
        LDB(1, cur);
        STAGEC(2, nxt, k0n);
        VM(4);
        BAR();
        MFMA16(0, 1);
        // ph2: read c1(t); stage c3(t+1); no wait, no barrier
        LDA(1, cur);
        STAGEC(3, nxt, k0n);
        MFMA16(1, 0);
        // ph3: stage c1(t+1); retire c0,c2(t+1) for next ph0
        STAGEC(1, nxt, k0n);
        VM(4);
        BAR();
        MFMA16(1, 1);
    }
    {   // Tail tile: queue holds [c3,c1]; drain 2 -> 0.
        const int cur = (nt - 1) & 1;
        LDA(0, cur); LDB(0, cur);
        VM(2);
        BAR();
        MFMA16(0, 0);
        LDB(1, cur);
        VM(0);
        BAR();
        MFMA16(0, 1);
        LDA(1, cur);
        MFMA16(1, 0);
        MFMA16(1, 1);
    }

    // Split-K partial store in MFMA-NATIVE layout, bf16x4-vectorized:
    // elem offset = blk*65536 + w*8192 + m*1024 + n*256 + l*4 + i.
    // Consecutive lanes -> consecutive 8B -> 512B contiguous per wave-store.
    {
        const int blk = (int)(o % (gridDim.x * gridDim.y));   // bm*gridDim.x + ... use bm,bn directly
        __bf16* pz = part + (size_t)bz * MN
                   + (size_t)(bm * (int)gridDim.x + bn) * 65536
                   + (size_t)(w * 8192 + l * 4);
#pragma unroll
        for (int m = 0; m < 8; ++m) {
#pragma unroll
            for (int n = 0; n < 4; ++n) {
                bf16x4 ov;
                ov[0] = (__bf16)acc[m][n][0];
                ov[1] = (__bf16)acc[m][n][1];
                ov[2] = (__bf16)acc[m][n][2];
                ov[3] = (__bf16)acc[m][n][3];
                *(bf16x4*)(pz + m * 1024 + n * 256) = ov;
            }
        }
        (void)blk;
    }
#undef STAGEC
#undef BAR
#undef VM
#undef LDA
#undef LDB
#undef MFMA16
}

// Epilogue: invert the native layout. Quad q (4 elems i=0..3):
// blk = q>>14; w=(q>>11)&7; m=(q>>8)&7; n=(q>>6)&3; l=q&63;
// row = (blk>>4)*256 + (w>>2)*128 + m*16 + (l>>4)*4 + i
// col = (blk&15)*256 + (w&3)*64 + n*16 + (l&15)
__global__ __launch_bounds__(256) void epilogue_kernel(
    const __bf16* __restrict__ part, int split, const float* __restrict__ xin,
    const float* __restrict__ Bin, float* __restrict__ out)
{
    unsigned q = blockIdx.x * 256u + threadIdx.x;   // 0 .. MN/4-1
    unsigned blk = q >> 14;
    unsigned w   = (q >> 11) & 7u;
    unsigned m   = (q >> 8) & 7u;
    unsigned n   = (q >> 6) & 3u;
    unsigned l   = q & 63u;
    unsigned r0  = (blk >> 4) * 256u + (w >> 2) * 128u + m * 16u + (l >> 4) * 4u;
    unsigned c   = (blk & 15u) * 256u + (w & 3u) * 64u + n * 16u + (l & 15u);

    size_t e = (size_t)q * 4;
    float s[4] = {};
    for (int z = 0; z < split; ++z) {
        bf16x4 p = *(const bf16x4*)(part + (size_t)z * MN + e);
#pragma unroll
        for (int i = 0; i < 4; ++i) s[i] += (float)p[i];
    }
    float bc = Bin[c];
#pragma unroll
    for (int i = 0; i < 4; ++i) {
        size_t oi = (size_t)(r0 + i) * NRES + c;
        out[oi] = 0.1f * xin[oi] + 0.9f * tanhf(s[i] + bc);
    }
}

extern "C" void kernel_launch(void* const* d_in, const int* in_sizes, int n_in,
                              void* d_out, int out_size, void* d_ws, size_t ws_size,
                              hipStream_t stream) {
    (void)in_sizes; (void)n_in; (void)out_size;
    const float* passed     = (const float*)d_in[0];
    const float* lastOutput = (const float*)d_in[1];
    const float* lastPred   = (const float*)d_in[2];
    const float* x          = (const float*)d_in[3];
    const float* prob       = (const float*)d_in[4];
    const float* rand_num   = (const float*)d_in[5];
    const float* W_in       = (const float*)d_in[6];
    const float* W_res      = (const float*)d_in[7];
    const float* W_out      = (const float*)d_in[8];
    const float* B_in       = (const float*)d_in[9];
    float* out = (float*)d_out;

    const size_t AB = (size_t)(NBATCH + NRES) * KT * 2;   // 47,841,280 B
    __bf16* Abuf = (__bf16*)d_ws;
    __bf16* Bbuf = (__bf16*)((char*)d_ws + (size_t)NBATCH * KT * 2);
    __bf16* part = (__bf16*)((char*)d_ws + AB);

    // ws-guarded split-K factor (deterministic: ws_size fixed per session)
    int split = 1;
    if (ws_size >= AB + 4 * MN * sizeof(__bf16))      split = 4;
    else if (ws_size >= AB + 2 * MN * sizeof(__bf16)) split = 2;

    pack_all<<<(BU + AU) / 256, 256, 0, stream>>>(
        x, passed, lastOutput, lastPred, prob, rand_num,
        W_res, W_in, W_out, Abuf, Bbuf);

    dim3 grid(NRES / 256, NBATCH / 256, split);
    gemm_kernel<<<grid, 512, 0, stream>>>(Abuf, Bbuf, part, split);

    epilogue_kernel<<<(unsigned)(MN / 4 / 256), 256, 0, stream>>>(
        part, split, x, B_in, out);
}